// Round 1
// baseline (261.263 us; speedup 1.0000x reference)
//
#include <hip/hip_runtime.h>

#define NB 32
#define LL 2048
#define CH 512
#define BQ 512
#define HH 1024
#define LDA 520   // LDS row stride (bf16 elems): +8 pad -> balanced banks for 32x32 A-frags

typedef __attribute__((ext_vector_type(8))) short bf16x8;
typedef __attribute__((ext_vector_type(16))) float f32x16;

__device__ __forceinline__ unsigned short f2bf(float x) {
  unsigned int u = __float_as_uint(x);
  u += 0x7FFFu + ((u >> 16) & 1u);   // round-to-nearest-even
  return (unsigned short)(u >> 16);
}

__device__ __forceinline__ float fast_tanh(float x) {
  // tanh(x) = 1 - 2/(e^{2x}+1); saturates correctly at +-inf
  float e = __expf(2.0f * x);
  return 1.0f - 2.0f * __builtin_amdgcn_rcpf(e + 1.0f);
}

// ---------------- res_qc[b][h] = query[b,:]·Wq[h,:] + bc[h] ----------------
__global__ __launch_bounds__(256) void k_resqc(const float* __restrict__ query,
                                               const float* __restrict__ Wq,
                                               const float* __restrict__ bc,
                                               float* __restrict__ resqc) {
  int gid = blockIdx.x * 256 + threadIdx.x;   // 32768
  int b = gid >> 10, h = gid & 1023;
  const float4* q4 = (const float4*)(query + (size_t)b * BQ);
  const float4* w4 = (const float4*)(Wq + (size_t)h * BQ);
  float acc = 0.f;
#pragma unroll 4
  for (int i = 0; i < BQ / 4; ++i) {
    float4 a = q4[i], w = w4[i];
    acc += a.x * w.x + a.y * w.y + a.z * w.z + a.w * w.w;
  }
  resqc[gid] = acc + bc[h];
}

// ---------------- Wc f32 -> bf16 ----------------
__global__ __launch_bounds__(256) void k_cvt_wc(const float* __restrict__ Wc,
                                                unsigned short* __restrict__ wcb) {
  int f = blockIdx.x * 256 + threadIdx.x;   // float4 idx, 131072 total
  float4 v = ((const float4*)Wc)[f];
  union { unsigned short s[4]; uint2 u; } p;
  p.s[0] = f2bf(v.x); p.s[1] = f2bf(v.y); p.s[2] = f2bf(v.z); p.s[3] = f2bf(v.w);
  ((uint2*)wcb)[f] = p.u;
}

// ---------------- main: logits[b][l] = sum_h Wo[h]*tanh(resqc[b][h] + ctx[b,l,:]·Wc[h,:]) ----
__global__ __launch_bounds__(256, 2) void k_logits(const float* __restrict__ ctx,
                                                   const unsigned short* __restrict__ wcb,
                                                   const float* __restrict__ resqc,
                                                   const float* __restrict__ Wo,
                                                   float* __restrict__ logits) {
  __shared__ unsigned short Alds[64 * LDA];
  __shared__ float qcl[HH];
  __shared__ float wol[HH];
  __shared__ float lsum[64];

  int t = threadIdx.x;
  int bid = blockIdx.x;            // 0..1023
  int b = bid >> 5;
  int row0 = (bid & 31) << 6;      // l-tile start

  if (t < 64) lsum[t] = 0.f;
#pragma unroll
  for (int i = 0; i < 4; ++i) {
    qcl[t + 256 * i] = resqc[b * HH + t + 256 * i];
    wol[t + 256 * i] = Wo[t + 256 * i];
  }
  // stage 64x512 f32 tile -> bf16 LDS (coalesced float4 reads)
  const float4* src = (const float4*)(ctx + ((size_t)(b * LL + row0)) * CH);
#pragma unroll 8
  for (int p = 0; p < 32; ++p) {
    int f = p * 256 + t;           // 8192 float4s
    int r = f >> 7, c4 = f & 127;
    float4 v = src[f];
    union { unsigned short s[4]; uint2 u; } pk;
    pk.s[0] = f2bf(v.x); pk.s[1] = f2bf(v.y); pk.s[2] = f2bf(v.z); pk.s[3] = f2bf(v.w);
    *(uint2*)(Alds + r * LDA + c4 * 4) = pk.u;
  }
  __syncthreads();

  int wave = t >> 6, lane = t & 63;
  int lo = lane & 31, hi = lane >> 5;

  const unsigned short* a0p = Alds + lo * LDA + hi * 8;
  const unsigned short* a1p = a0p + 32 * LDA;

  float p0[16], p1[16];
#pragma unroll
  for (int r = 0; r < 16; ++r) { p0[r] = 0.f; p1[r] = 0.f; }

#pragma unroll
  for (int g = 0; g < 4; ++g) {
    int n0 = wave * 256 + g * 64;  // this wave covers cols [wave*256, wave*256+256)
    const bf16x8* bAp = (const bf16x8*)(wcb + (size_t)(n0 + lo) * CH + hi * 8);
    const bf16x8* bBp = (const bf16x8*)(wcb + (size_t)(n0 + 32 + lo) * CH + hi * 8);
    f32x16 acc00 = {0,0,0,0,0,0,0,0,0,0,0,0,0,0,0,0};
    f32x16 acc01 = {0,0,0,0,0,0,0,0,0,0,0,0,0,0,0,0};
    f32x16 acc10 = {0,0,0,0,0,0,0,0,0,0,0,0,0,0,0,0};
    f32x16 acc11 = {0,0,0,0,0,0,0,0,0,0,0,0,0,0,0,0};
#pragma unroll 4
    for (int ks = 0; ks < 32; ++ks) {           // K = 512 / 16
      bf16x8 fa0 = *(const bf16x8*)(a0p + ks * 16);
      bf16x8 fa1 = *(const bf16x8*)(a1p + ks * 16);
      bf16x8 fb0 = bAp[2 * ks];
      bf16x8 fb1 = bBp[2 * ks];
      acc00 = __builtin_amdgcn_mfma_f32_32x32x16_bf16(fa0, fb0, acc00, 0, 0, 0);
      acc01 = __builtin_amdgcn_mfma_f32_32x32x16_bf16(fa0, fb1, acc01, 0, 0, 0);
      acc10 = __builtin_amdgcn_mfma_f32_32x32x16_bf16(fa1, fb0, acc10, 0, 0, 0);
      acc11 = __builtin_amdgcn_mfma_f32_32x32x16_bf16(fa1, fb1, acc11, 0, 0, 0);
    }
    float qA = qcl[n0 + lo], qB = qcl[n0 + 32 + lo];
    float wA = wol[n0 + lo], wB = wol[n0 + 32 + lo];
#pragma unroll
    for (int r = 0; r < 16; ++r) {
      p0[r] += wA * fast_tanh(acc00[r] + qA) + wB * fast_tanh(acc01[r] + qB);
      p1[r] += wA * fast_tanh(acc10[r] + qA) + wB * fast_tanh(acc11[r] + qB);
    }
  }
  // butterfly over the 32-lane halves (cols); rows stay lane-local
#pragma unroll
  for (int m = 16; m >= 1; m >>= 1) {
#pragma unroll
    for (int r = 0; r < 16; ++r) {
      p0[r] += __shfl_xor(p0[r], m, 64);
      p1[r] += __shfl_xor(p1[r], m, 64);
    }
  }
  if (lo == 0) {
#pragma unroll
    for (int r = 0; r < 16; ++r) {
      int row_a = (r & 3) + 8 * (r >> 2) + 4 * hi;   // verified 32x32 C/D row map
      atomicAdd(&lsum[row_a], p0[r]);
      atomicAdd(&lsum[32 + row_a], p1[r]);
    }
  }
  __syncthreads();
  if (t < 64) logits[(size_t)b * LL + row0 + t] = lsum[t];
}

// ---------------- weights: in-place mask*exp + normalize over L ----------------
__global__ __launch_bounds__(256) void k_weights(const float* __restrict__ mask,
                                                 const float* __restrict__ bo,
                                                 float* __restrict__ wout) {
  __shared__ float red[4];
  int b = blockIdx.x, t = threadIdx.x;
  float bov = bo[0];
  float w[8];
  float s = 0.f;
#pragma unroll
  for (int i = 0; i < 8; ++i) {
    int l = t + 256 * i;
    float e = mask[b * LL + l] * __expf(wout[b * LL + l] + bov);
    w[i] = e; s += e;
  }
#pragma unroll
  for (int m = 32; m >= 1; m >>= 1) s += __shfl_xor(s, m, 64);
  int wave = t >> 6, lane = t & 63;
  if (lane == 0) red[wave] = s;
  __syncthreads();
  float inv = 1.0f / (red[0] + red[1] + red[2] + red[3] + 1e-5f);
#pragma unroll
  for (int i = 0; i < 8; ++i) wout[b * LL + t + 256 * i] = w[i] * inv;
}

// ---------------- output[b][c] = sum_l weights[b][l] * ctx[b][l][c] ----------------
__global__ __launch_bounds__(256) void k_output(const float* __restrict__ ctx,
                                                const float* __restrict__ weights,
                                                float* __restrict__ out) {
  __shared__ float wl[128];
  int bid = blockIdx.x;            // 512 = 32 b * 16 chunks
  int b = bid >> 4, chunk = bid & 15;
  int t = threadIdx.x;
  int l0 = chunk * 128;
  if (t < 128) wl[t] = weights[b * LL + l0 + t];
  __syncthreads();
  const float2* c2 = (const float2*)(ctx + ((size_t)(b * LL + l0)) * CH) + t;
  float ax = 0.f, ay = 0.f;
#pragma unroll 4
  for (int l = 0; l < 128; ++l) {
    float wv = wl[l];
    float2 v = c2[(size_t)l * (CH / 2)];
    ax += wv * v.x; ay += wv * v.y;
  }
  atomicAdd(&out[b * CH + 2 * t], ax);
  atomicAdd(&out[b * CH + 2 * t + 1], ay);
}

extern "C" void kernel_launch(void* const* d_in, const int* in_sizes, int n_in,
                              void* d_out, int out_size, void* d_ws, size_t ws_size,
                              hipStream_t stream) {
  const float* query = (const float*)d_in[0];
  const float* ctx   = (const float*)d_in[1];
  const float* mask  = (const float*)d_in[2];
  const float* Wq    = (const float*)d_in[3];
  const float* Wc    = (const float*)d_in[4];
  const float* bc    = (const float*)d_in[5];
  const float* Wo    = (const float*)d_in[6];
  const float* bo    = (const float*)d_in[7];
  float* out = (float*)d_out;

  unsigned short* wcb = (unsigned short*)d_ws;                    // 1 MB bf16 Wc
  float* resqc = (float*)((char*)d_ws + (1 << 20));               // 128 KB
  float* wout = out + NB * CH;                                    // logits->weights slot

  hipMemsetAsync(out, 0, NB * CH * sizeof(float), stream);        // zero output region
  k_resqc<<<128, 256, 0, stream>>>(query, Wq, bc, resqc);
  k_cvt_wc<<<512, 256, 0, stream>>>(Wc, wcb);
  k_logits<<<1024, 256, 0, stream>>>(ctx, wcb, resqc, Wo, wout);
  k_weights<<<32, 256, 0, stream>>>(mask, bo, wout);
  k_output<<<512, 256, 0, stream>>>(ctx, wout, out);
}

// Round 2
// 185.491 us; speedup vs baseline: 1.4085x; 1.4085x over previous
//
#include <hip/hip_runtime.h>

#define NB 32
#define LL 2048
#define CH 512
#define BQ 512
#define HH 1024

typedef __attribute__((ext_vector_type(8))) short bf16x8;
typedef __attribute__((ext_vector_type(16))) float f32x16;

__device__ __forceinline__ unsigned short f2bf(float x) {
  unsigned int u = __float_as_uint(x);
  u += 0x7FFFu + ((u >> 16) & 1u);   // round-to-nearest-even
  return (unsigned short)(u >> 16);
}

__device__ __forceinline__ float fast_tanh(float x) {
  // tanh(x) = 1 - 2/(e^{2x}+1); saturates correctly at +-inf
  float e = __expf(2.0f * x);
  return 1.0f - 2.0f * __builtin_amdgcn_rcpf(e + 1.0f);
}

// ---------------- res_qc[b][h] = query[b,:]·Wq[h,:] + bc[h] ----------------
__global__ __launch_bounds__(256) void k_resqc(const float* __restrict__ query,
                                               const float* __restrict__ Wq,
                                               const float* __restrict__ bc,
                                               float* __restrict__ resqc) {
  int gid = blockIdx.x * 256 + threadIdx.x;   // 32768
  int b = gid >> 10, h = gid & 1023;
  const float4* q4 = (const float4*)(query + (size_t)b * BQ);
  const float4* w4 = (const float4*)(Wq + (size_t)h * BQ);
  float acc = 0.f;
#pragma unroll 4
  for (int i = 0; i < BQ / 4; ++i) {
    float4 a = q4[i], w = w4[i];
    acc += a.x * w.x + a.y * w.y + a.z * w.z + a.w * w.w;
  }
  resqc[gid] = acc + bc[h];
}

// ---------------- Wc f32 -> bf16 ----------------
__global__ __launch_bounds__(256) void k_cvt_wc(const float* __restrict__ Wc,
                                                unsigned short* __restrict__ wcb) {
  int f = blockIdx.x * 256 + threadIdx.x;   // float4 idx, 131072 total
  float4 v = ((const float4*)Wc)[f];
  union { unsigned short s[4]; uint2 u; } p;
  p.s[0] = f2bf(v.x); p.s[1] = f2bf(v.y); p.s[2] = f2bf(v.z); p.s[3] = f2bf(v.w);
  ((uint2*)wcb)[f] = p.u;
}

// ---------------- main: logits[b][l] = sum_h Wo[h]*tanh(resqc[b][h] + ctx[b,l,:]·Wc[h,:]) ----
// 512 threads = 8 waves; M=64 rows, N=1024 (wave owns 128 cols in 2 groups of 64).
// A tile 64x512 bf16 in LDS, XOR-swizzled (byte ^= (row&7)<<4) -> conflict-free b128.
__global__ __launch_bounds__(512, 4) void k_logits(const float* __restrict__ ctx,
                                                   const unsigned short* __restrict__ wcb,
                                                   const float* __restrict__ resqc,
                                                   const float* __restrict__ Wo,
                                                   float* __restrict__ logits) {
  __shared__ unsigned short Alds[64 * 512];   // 64 KB
  __shared__ float lsum[64];

  int t = threadIdx.x;
  int bid = blockIdx.x;            // 0..1023
  int b = bid >> 5;
  int row0 = (bid & 31) << 6;      // l-tile start

  if (t < 64) lsum[t] = 0.f;

  // stage 64x512 f32 -> bf16 LDS, swizzled. 512 thr x 16 float4 = 8192 float4.
  const float4* src = (const float4*)(ctx + ((size_t)(b * LL + row0)) * CH);
  char* abase = (char*)Alds;
#pragma unroll
  for (int p = 0; p < 16; ++p) {
    int f = p * 512 + t;
    int r = f >> 7, c4 = f & 127;          // row, float4-col (128 per row)
    float4 v = src[f];
    union { unsigned short s[4]; uint2 u; } pk;
    pk.s[0] = f2bf(v.x); pk.s[1] = f2bf(v.y); pk.s[2] = f2bf(v.z); pk.s[3] = f2bf(v.w);
    int X = (c4 * 8) ^ ((r & 7) << 4);     // swizzled byte offset within row
    *(uint2*)(abase + r * 1024 + X) = pk.u;
  }
  __syncthreads();

  int wave = t >> 6, lane = t & 63;
  int lo = lane & 31, hi = lane >> 5;
  int swz = (lo & 7) << 4;
  const char* a0b = abase + lo * 1024;
  const char* a1b = abase + (32 + lo) * 1024;

#pragma unroll
  for (int g = 0; g < 2; ++g) {
    int n0 = wave * 128 + g * 64;          // this wave+group covers cols [n0, n0+64)
    const bf16x8* bAp = (const bf16x8*)(wcb + (size_t)(n0 + lo) * CH + hi * 8);
    const bf16x8* bBp = (const bf16x8*)(wcb + (size_t)(n0 + 32 + lo) * CH + hi * 8);
    f32x16 acc00 = {0,0,0,0,0,0,0,0,0,0,0,0,0,0,0,0};
    f32x16 acc01 = {0,0,0,0,0,0,0,0,0,0,0,0,0,0,0,0};
    f32x16 acc10 = {0,0,0,0,0,0,0,0,0,0,0,0,0,0,0,0};
    f32x16 acc11 = {0,0,0,0,0,0,0,0,0,0,0,0,0,0,0,0};
#pragma unroll 8
    for (int ks = 0; ks < 32; ++ks) {           // K = 512 / 16
      int X = (hi * 16 + ks * 32) ^ swz;
      bf16x8 fa0 = *(const bf16x8*)(a0b + X);
      bf16x8 fa1 = *(const bf16x8*)(a1b + X);
      bf16x8 fb0 = bAp[2 * ks];
      bf16x8 fb1 = bBp[2 * ks];
      acc00 = __builtin_amdgcn_mfma_f32_32x32x16_bf16(fa0, fb0, acc00, 0, 0, 0);
      acc01 = __builtin_amdgcn_mfma_f32_32x32x16_bf16(fa0, fb1, acc01, 0, 0, 0);
      acc10 = __builtin_amdgcn_mfma_f32_32x32x16_bf16(fa1, fb0, acc10, 0, 0, 0);
      acc11 = __builtin_amdgcn_mfma_f32_32x32x16_bf16(fa1, fb1, acc11, 0, 0, 0);
    }
    float qA = resqc[b * HH + n0 + lo], qB = resqc[b * HH + n0 + 32 + lo];
    float wA = Wo[n0 + lo],             wB = Wo[n0 + 32 + lo];
    float p0[16], p1[16];
#pragma unroll
    for (int r = 0; r < 16; ++r) {
      p0[r] = wA * fast_tanh(acc00[r] + qA) + wB * fast_tanh(acc01[r] + qB);
      p1[r] = wA * fast_tanh(acc10[r] + qA) + wB * fast_tanh(acc11[r] + qB);
    }
    // butterfly over the 32-lane halves (cols); rows stay lane-local
#pragma unroll
    for (int m = 16; m >= 1; m >>= 1) {
#pragma unroll
      for (int r = 0; r < 16; ++r) {
        p0[r] += __shfl_xor(p0[r], m, 64);
        p1[r] += __shfl_xor(p1[r], m, 64);
      }
    }
    if (lo == 0) {
#pragma unroll
      for (int r = 0; r < 16; ++r) {
        int row_a = (r & 3) + 8 * (r >> 2) + 4 * hi;   // verified 32x32 C/D row map
        atomicAdd(&lsum[row_a], p0[r]);
        atomicAdd(&lsum[32 + row_a], p1[r]);
      }
    }
  }
  __syncthreads();
  if (t < 64) logits[(size_t)b * LL + row0 + t] = lsum[t];
}

// ---------------- weights: in-place mask*exp + normalize over L ----------------
__global__ __launch_bounds__(256) void k_weights(const float* __restrict__ mask,
                                                 const float* __restrict__ bo,
                                                 float* __restrict__ wout) {
  __shared__ float red[4];
  int b = blockIdx.x, t = threadIdx.x;
  float bov = bo[0];
  float w[8];
  float s = 0.f;
#pragma unroll
  for (int i = 0; i < 8; ++i) {
    int l = t + 256 * i;
    float e = mask[b * LL + l] * __expf(wout[b * LL + l] + bov);
    w[i] = e; s += e;
  }
#pragma unroll
  for (int m = 32; m >= 1; m >>= 1) s += __shfl_xor(s, m, 64);
  int wave = t >> 6, lane = t & 63;
  if (lane == 0) red[wave] = s;
  __syncthreads();
  float inv = 1.0f / (red[0] + red[1] + red[2] + red[3] + 1e-5f);
#pragma unroll
  for (int i = 0; i < 8; ++i) wout[b * LL + t + 256 * i] = w[i] * inv;
}

// ---------------- output[b][c] = sum_l weights[b][l] * ctx[b][l][c] ----------------
__global__ __launch_bounds__(256) void k_output(const float* __restrict__ ctx,
                                                const float* __restrict__ weights,
                                                float* __restrict__ out) {
  __shared__ float wl[128];
  int bid = blockIdx.x;            // 512 = 32 b * 16 chunks
  int b = bid >> 4, chunk = bid & 15;
  int t = threadIdx.x;
  int l0 = chunk * 128;
  if (t < 128) wl[t] = weights[b * LL + l0 + t];
  __syncthreads();
  const float2* c2 = (const float2*)(ctx + ((size_t)(b * LL + l0)) * CH) + t;
  float ax = 0.f, ay = 0.f;
#pragma unroll 4
  for (int l = 0; l < 128; ++l) {
    float wv = wl[l];
    float2 v = c2[(size_t)l * (CH / 2)];
    ax += wv * v.x; ay += wv * v.y;
  }
  atomicAdd(&out[b * CH + 2 * t], ax);
  atomicAdd(&out[b * CH + 2 * t + 1], ay);
}

extern "C" void kernel_launch(void* const* d_in, const int* in_sizes, int n_in,
                              void* d_out, int out_size, void* d_ws, size_t ws_size,
                              hipStream_t stream) {
  const float* query = (const float*)d_in[0];
  const float* ctx   = (const float*)d_in[1];
  const float* mask  = (const float*)d_in[2];
  const float* Wq    = (const float*)d_in[3];
  const float* Wc    = (const float*)d_in[4];
  const float* bc    = (const float*)d_in[5];
  const float* Wo    = (const float*)d_in[6];
  const float* bo    = (const float*)d_in[7];
  float* out = (float*)d_out;

  unsigned short* wcb = (unsigned short*)d_ws;                    // 1 MB bf16 Wc
  float* resqc = (float*)((char*)d_ws + (1 << 20));               // 128 KB
  float* wout = out + NB * CH;                                    // logits->weights slot

  hipMemsetAsync(out, 0, NB * CH * sizeof(float), stream);        // zero output region
  k_resqc<<<128, 256, 0, stream>>>(query, Wq, bc, resqc);
  k_cvt_wc<<<512, 256, 0, stream>>>(Wc, wcb);
  k_logits<<<1024, 512, 0, stream>>>(ctx, wcb, resqc, Wo, wout);
  k_weights<<<32, 256, 0, stream>>>(mask, bo, wout);
  k_output<<<512, 256, 0, stream>>>(ctx, wout, out);
}